// Round 1
// baseline (1243.082 us; speedup 1.0000x reference)
//
#include <hip/hip_runtime.h>
#include <math.h>

#define B_   64
#define S_   197
#define D_   768
#define H_   12
#define HD_  64
#define M_   (B_ * S_)   // 12608, divisible by 64

// ---------------------------------------------------------------------------
// C[M,768] = A[M,768] @ W[768,768] + bias[768]
// 64x64 block tile, BK=16, 256 threads, 4x4 micro-tile per thread.
// ---------------------------------------------------------------------------
__global__ __launch_bounds__(256) void gemm_bias_kernel(
    const float* __restrict__ A, const float* __restrict__ W,
    const float* __restrict__ bias, float* __restrict__ C)
{
    __shared__ float As[16][64];   // [k][m]  (transposed on store)
    __shared__ float Bs[16][64];   // [k][n]
    const int tid = threadIdx.x;
    const int tx = tid & 15, ty = tid >> 4;
    const int m0 = blockIdx.y * 64;
    const int n0 = blockIdx.x * 64;

    // A-tile load mapping: 64 rows x 16 k, one float4 per thread
    const int ar = (tid * 4) >> 4;   // 0..63
    const int ac = (tid * 4) & 15;   // 0,4,8,12
    // W-tile load mapping: 16 k x 64 n, one float4 per thread
    const int br = tid >> 4;         // 0..15
    const int bc = (tid & 15) * 4;   // 0..60

    float acc[4][4] = {{0.f,0.f,0.f,0.f},{0.f,0.f,0.f,0.f},
                       {0.f,0.f,0.f,0.f},{0.f,0.f,0.f,0.f}};

    for (int k0 = 0; k0 < D_; k0 += 16) {
        const float4 av = *(const float4*)&A[(size_t)(m0 + ar) * D_ + k0 + ac];
        const float4 bv = *(const float4*)&W[(size_t)(k0 + br) * D_ + n0 + bc];
        As[ac + 0][ar] = av.x; As[ac + 1][ar] = av.y;
        As[ac + 2][ar] = av.z; As[ac + 3][ar] = av.w;
        *(float4*)&Bs[br][bc] = bv;
        __syncthreads();
        #pragma unroll
        for (int kk = 0; kk < 16; ++kk) {
            const float4 a4 = *(const float4*)&As[kk][ty * 4];
            const float4 b4 = *(const float4*)&Bs[kk][tx * 4];
            const float ax[4] = {a4.x, a4.y, a4.z, a4.w};
            const float bx[4] = {b4.x, b4.y, b4.z, b4.w};
            #pragma unroll
            for (int i = 0; i < 4; ++i)
                #pragma unroll
                for (int j = 0; j < 4; ++j)
                    acc[i][j] += ax[i] * bx[j];
        }
        __syncthreads();
    }

    const float4 bb = *(const float4*)&bias[n0 + tx * 4];
    const float badd[4] = {bb.x, bb.y, bb.z, bb.w};
    #pragma unroll
    for (int i = 0; i < 4; ++i) {
        float4 o;
        o.x = acc[i][0] + badd[0];
        o.y = acc[i][1] + badd[1];
        o.z = acc[i][2] + badd[2];
        o.w = acc[i][3] + badd[3];
        *(float4*)&C[(size_t)(m0 + ty * 4 + i) * D_ + n0 + tx * 4] = o;
    }
}

// ---------------------------------------------------------------------------
// P[bh, r, d] = sum_s E[s, r] * KV[b, s, h*64 + d]
// One block per (b,h). 64x64 output, K-dim = 197 staged in chunks of 64.
// ---------------------------------------------------------------------------
__global__ __launch_bounds__(256) void project_kernel(
    const float* __restrict__ KV, const float* __restrict__ E,
    float* __restrict__ P)
{
    const int bh = blockIdx.x;
    const int b = bh / H_, h = bh % H_;
    __shared__ float Es[64][64];   // [s][r]
    __shared__ float Ks[64][64];   // [s][d]
    const int tid = threadIdx.x;
    const int tx = tid & 15, ty = tid >> 4;

    float acc[4][4] = {{0.f,0.f,0.f,0.f},{0.f,0.f,0.f,0.f},
                       {0.f,0.f,0.f,0.f},{0.f,0.f,0.f,0.f}};

    for (int s0 = 0; s0 < S_; s0 += 64) {
        #pragma unroll
        for (int i = 0; i < 4; ++i) {
            const int flat = i * 1024 + tid * 4;
            const int ss = flat >> 6, cc = flat & 63;
            const int s = s0 + ss;
            float4 ev = make_float4(0.f, 0.f, 0.f, 0.f);
            float4 kv = make_float4(0.f, 0.f, 0.f, 0.f);
            if (s < S_) {
                ev = *(const float4*)&E[s * HD_ + cc];
                kv = *(const float4*)&KV[((size_t)(b * S_ + s)) * D_ + h * HD_ + cc];
            }
            *(float4*)&Es[ss][cc] = ev;
            *(float4*)&Ks[ss][cc] = kv;
        }
        __syncthreads();
        #pragma unroll 8
        for (int ss = 0; ss < 64; ++ss) {
            const float4 a4 = *(const float4*)&Es[ss][ty * 4];
            const float4 b4 = *(const float4*)&Ks[ss][tx * 4];
            const float ax[4] = {a4.x, a4.y, a4.z, a4.w};
            const float bx[4] = {b4.x, b4.y, b4.z, b4.w};
            #pragma unroll
            for (int i = 0; i < 4; ++i)
                #pragma unroll
                for (int j = 0; j < 4; ++j)
                    acc[i][j] += ax[i] * bx[j];
        }
        __syncthreads();
    }

    #pragma unroll
    for (int i = 0; i < 4; ++i) {
        float4 o = {acc[i][0], acc[i][1], acc[i][2], acc[i][3]};
        *(float4*)&P[(size_t)bh * 4096 + (ty * 4 + i) * HD_ + tx * 4] = o;
    }
}

// ---------------------------------------------------------------------------
// Attention core: one block per (b,h); pk/pv resident in LDS.
// Wave w handles rows s = w, w+4, ...  Lane l computes score for r=l,
// then ctx for d=l.  Cross-lane broadcast via __shfl (wave=64, no LDS sync).
// ---------------------------------------------------------------------------
__global__ __launch_bounds__(256) void attn_kernel(
    const float* __restrict__ Q, const float* __restrict__ PK,
    const float* __restrict__ PV, float* __restrict__ CTX)
{
    const int bh = blockIdx.x;
    const int b = bh / H_, h = bh % H_;
    __shared__ float pk[64][65];   // [r][d], pad -> conflict-free [lane][dd]
    __shared__ float pv[64][65];   // [r][d]
    const int tid = threadIdx.x;
    const int w = tid >> 6, lane = tid & 63;

    #pragma unroll
    for (int i = 0; i < 4; ++i) {
        const int flat = i * 1024 + tid * 4;
        const int r = flat >> 6, c = flat & 63;
        const float4 kq = *(const float4*)&PK[(size_t)bh * 4096 + flat];
        const float4 vq = *(const float4*)&PV[(size_t)bh * 4096 + flat];
        pk[r][c + 0] = kq.x; pk[r][c + 1] = kq.y;
        pk[r][c + 2] = kq.z; pk[r][c + 3] = kq.w;
        pv[r][c + 0] = vq.x; pv[r][c + 1] = vq.y;
        pv[r][c + 2] = vq.z; pv[r][c + 3] = vq.w;
    }
    __syncthreads();

    for (int s = w; s < S_; s += 4) {
        const float q = Q[((size_t)(b * S_ + s)) * D_ + h * HD_ + lane];
        // scores[r=lane] = sum_d q[d] * pk[lane][d]
        float sc = 0.f;
        #pragma unroll
        for (int dd = 0; dd < 64; ++dd)
            sc += __shfl(q, dd, 64) * pk[lane][dd];
        sc *= 0.125f;   // 1/sqrt(64)
        // softmax over the 64 lanes
        float m = sc;
        #pragma unroll
        for (int off = 32; off >= 1; off >>= 1)
            m = fmaxf(m, __shfl_xor(m, off, 64));
        float p = __expf(sc - m);
        float sum = p;
        #pragma unroll
        for (int off = 32; off >= 1; off >>= 1)
            sum += __shfl_xor(sum, off, 64);
        p /= sum;
        // ctx[d=lane] = sum_r p[r] * pv[r][lane]
        float cv = 0.f;
        #pragma unroll
        for (int r = 0; r < 64; ++r)
            cv += __shfl(p, r, 64) * pv[r][lane];
        CTX[((size_t)(b * S_ + s)) * D_ + h * HD_ + lane] = cv;
    }
}

// ---------------------------------------------------------------------------
extern "C" void kernel_launch(void* const* d_in, const int* in_sizes, int n_in,
                              void* d_out, int out_size, void* d_ws, size_t ws_size,
                              hipStream_t stream) {
    const float* X   = (const float*)d_in[0];
    const float* Wq  = (const float*)d_in[1];
    const float* bq  = (const float*)d_in[2];
    const float* Wk  = (const float*)d_in[3];
    const float* bk  = (const float*)d_in[4];
    const float* Wv  = (const float*)d_in[5];
    const float* bv  = (const float*)d_in[6];
    const float* Wo  = (const float*)d_in[7];
    const float* bo  = (const float*)d_in[8];
    const float* E_k = (const float*)d_in[9];
    const float* E_v = (const float*)d_in[10];
    float* out = (float*)d_out;

    float* buf1 = (float*)d_ws;                         // k, then v, then q
    float* ctx  = buf1 + (size_t)M_ * D_;               // attention output
    float* pk   = ctx  + (size_t)M_ * D_;               // [768,64,64]
    float* pv   = pk   + (size_t)(B_ * H_) * 64 * 64;

    const dim3 gg(D_ / 64, M_ / 64);   // (12, 197)

    gemm_bias_kernel<<<gg, 256, 0, stream>>>(X, Wk, bk, buf1);        // k
    project_kernel <<<B_ * H_, 256, 0, stream>>>(buf1, E_k, pk);      // pk
    gemm_bias_kernel<<<gg, 256, 0, stream>>>(X, Wv, bv, buf1);        // v
    project_kernel <<<B_ * H_, 256, 0, stream>>>(buf1, E_v, pv);      // pv
    gemm_bias_kernel<<<gg, 256, 0, stream>>>(X, Wq, bq, buf1);        // q
    attn_kernel    <<<B_ * H_, 256, 0, stream>>>(buf1, pk, pv, ctx);  // ctx
    gemm_bias_kernel<<<gg, 256, 0, stream>>>(ctx, Wo, bo, out);       // out
}

// Round 2
// 491.089 us; speedup vs baseline: 2.5313x; 2.5313x over previous
//
#include <hip/hip_runtime.h>
#include <math.h>

#define B_   64
#define S_   197
#define D_   768
#define H_   12
#define HD_  64
#define M_   (B_ * S_)     // 12608
#define MPAD 12672         // 99 * 128

typedef _Float16 half8_t __attribute__((ext_vector_type(8)));
typedef _Float16 half4_t __attribute__((ext_vector_type(4)));
typedef float floatx4 __attribute__((ext_vector_type(4)));

// ---------------------------------------------------------------------------
// fp32 -> fp16 convert with zero-padding of rows beyond M_.
// validN and totalN are element counts, both divisible by 4.
// ---------------------------------------------------------------------------
__global__ __launch_bounds__(256) void conv_x_kernel(
    const float* __restrict__ X, _Float16* __restrict__ Xh,
    int validN, int totalN)
{
    const int i4 = (blockIdx.x * 256 + threadIdx.x) * 4;
    if (i4 >= totalN) return;
    float4 v = make_float4(0.f, 0.f, 0.f, 0.f);
    if (i4 < validN) v = *(const float4*)&X[i4];
    half4_t o = { (_Float16)v.x, (_Float16)v.y, (_Float16)v.z, (_Float16)v.w };
    *(half4_t*)&Xh[i4] = o;
}

// ---------------------------------------------------------------------------
// Transpose+convert the 4 weight matrices: T[n][k] = (fp16) W[k][n], 768x768.
// grid (24,24,4), 32x32 tiles.
// ---------------------------------------------------------------------------
__global__ __launch_bounds__(256) void transpose_w_kernel(
    const float* __restrict__ W0, const float* __restrict__ W1,
    const float* __restrict__ W2, const float* __restrict__ W3,
    _Float16* __restrict__ T0, _Float16* __restrict__ T1,
    _Float16* __restrict__ T2, _Float16* __restrict__ T3)
{
    const float* W = (blockIdx.z == 0) ? W0 : (blockIdx.z == 1) ? W1
                   : (blockIdx.z == 2) ? W2 : W3;
    _Float16* T = (blockIdx.z == 0) ? T0 : (blockIdx.z == 1) ? T1
                : (blockIdx.z == 2) ? T2 : T3;
    __shared__ float tile[32][33];
    const int n0 = blockIdx.x * 32, k0 = blockIdx.y * 32;
    const int r = threadIdx.x >> 3, c4 = (threadIdx.x & 7) * 4;
    *(float4*)&tile[r][c4] = *(const float4*)&W[(size_t)(k0 + r) * D_ + n0 + c4];
    __syncthreads();
    half4_t o = { (_Float16)tile[c4 + 0][r], (_Float16)tile[c4 + 1][r],
                  (_Float16)tile[c4 + 2][r], (_Float16)tile[c4 + 3][r] };
    *(half4_t*)&T[(size_t)(n0 + r) * D_ + k0 + c4] = o;
}

// ---------------------------------------------------------------------------
// C[m,n] = A[m,:] . Bt[n,:] + bias[n]   (fp16 inputs, fp32 accumulate/output)
// A: [MPAD][768] fp16,  Bt: [768][768] fp16 (pre-transposed weight)
// 128x128 tile, BK=32, 256 threads = 2x2 waves, each wave 4x4 MFMA frags.
// ---------------------------------------------------------------------------
__global__ __launch_bounds__(256) void gemm_f16_kernel(
    const _Float16* __restrict__ A, const _Float16* __restrict__ Bt,
    const float* __restrict__ bias, float* __restrict__ C, int guardM)
{
    __shared__ _Float16 Ah[128][32];
    __shared__ _Float16 Bh[128][32];
    const int tid = threadIdx.x;
    const int m0 = blockIdx.y * 128;
    const int n0 = blockIdx.x * 128;
    const int wave = tid >> 6, lane = tid & 63;
    const int wm = (wave >> 1) * 64, wn = (wave & 1) * 64;
    const int sr = tid >> 1;             // staging row 0..127
    const int sc = (tid & 1) * 16;       // staging col 0 or 16

    const _Float16* Aptr = A + (size_t)(m0 + sr) * D_ + sc;
    const _Float16* Bptr = Bt + (size_t)(n0 + sr) * D_ + sc;

    floatx4 acc[4][4] = {};
    const int fr = lane & 15, kofs = (lane >> 4) * 8;

    for (int k0 = 0; k0 < D_; k0 += 32) {
        *(half8_t*)&Ah[sr][sc]     = *(const half8_t*)(Aptr + k0);
        *(half8_t*)&Ah[sr][sc + 8] = *(const half8_t*)(Aptr + k0 + 8);
        *(half8_t*)&Bh[sr][sc]     = *(const half8_t*)(Bptr + k0);
        *(half8_t*)&Bh[sr][sc + 8] = *(const half8_t*)(Bptr + k0 + 8);
        __syncthreads();
        half8_t af[4], bf[4];
        #pragma unroll
        for (int i = 0; i < 4; ++i) {
            af[i] = *(const half8_t*)&Ah[wm + i * 16 + fr][kofs];
            bf[i] = *(const half8_t*)&Bh[wn + i * 16 + fr][kofs];
        }
        #pragma unroll
        for (int mi = 0; mi < 4; ++mi)
            #pragma unroll
            for (int ni = 0; ni < 4; ++ni)
                acc[mi][ni] = __builtin_amdgcn_mfma_f32_16x16x32_f16(
                    af[mi], bf[ni], acc[mi][ni], 0, 0, 0);
        __syncthreads();
    }

    const int col = lane & 15, rq = (lane >> 4) * 4;
    #pragma unroll
    for (int ni = 0; ni < 4; ++ni) {
        const int n = n0 + wn + ni * 16 + col;
        const float bv = bias[n];
        #pragma unroll
        for (int mi = 0; mi < 4; ++mi) {
            #pragma unroll
            for (int i = 0; i < 4; ++i) {
                const int m = m0 + wm + mi * 16 + rq + i;
                if (m < guardM)
                    C[(size_t)m * D_ + n] = acc[mi][ni][i] + bv;
            }
        }
    }
}

// ---------------------------------------------------------------------------
// P[bh, r, d] = sum_s E[s, r] * KV[b, s, h*64 + d]   (fp32)
// ---------------------------------------------------------------------------
__global__ __launch_bounds__(256) void project_kernel(
    const float* __restrict__ KV, const float* __restrict__ E,
    float* __restrict__ P)
{
    const int bh = blockIdx.x;
    const int b = bh / H_, h = bh % H_;
    __shared__ float Es[64][64];
    __shared__ float Ks[64][64];
    const int tid = threadIdx.x;
    const int tx = tid & 15, ty = tid >> 4;

    float acc[4][4] = {{0.f,0.f,0.f,0.f},{0.f,0.f,0.f,0.f},
                       {0.f,0.f,0.f,0.f},{0.f,0.f,0.f,0.f}};

    for (int s0 = 0; s0 < S_; s0 += 64) {
        #pragma unroll
        for (int i = 0; i < 4; ++i) {
            const int flat = i * 1024 + tid * 4;
            const int ss = flat >> 6, cc = flat & 63;
            const int s = s0 + ss;
            float4 ev = make_float4(0.f, 0.f, 0.f, 0.f);
            float4 kv = make_float4(0.f, 0.f, 0.f, 0.f);
            if (s < S_) {
                ev = *(const float4*)&E[s * HD_ + cc];
                kv = *(const float4*)&KV[((size_t)(b * S_ + s)) * D_ + h * HD_ + cc];
            }
            *(float4*)&Es[ss][cc] = ev;
            *(float4*)&Ks[ss][cc] = kv;
        }
        __syncthreads();
        #pragma unroll 8
        for (int ss = 0; ss < 64; ++ss) {
            const float4 a4 = *(const float4*)&Es[ss][ty * 4];
            const float4 b4 = *(const float4*)&Ks[ss][tx * 4];
            const float ax[4] = {a4.x, a4.y, a4.z, a4.w};
            const float bx[4] = {b4.x, b4.y, b4.z, b4.w};
            #pragma unroll
            for (int i = 0; i < 4; ++i)
                #pragma unroll
                for (int j = 0; j < 4; ++j)
                    acc[i][j] += ax[i] * bx[j];
        }
        __syncthreads();
    }

    #pragma unroll
    for (int i = 0; i < 4; ++i) {
        float4 o = {acc[i][0], acc[i][1], acc[i][2], acc[i][3]};
        *(float4*)&P[(size_t)bh * 4096 + (ty * 4 + i) * HD_ + tx * 4] = o;
    }
}

// ---------------------------------------------------------------------------
// Attention core, register-tiled: per (b,h), per 64-row s-chunk:
//   scores = Q . pk^T * scale  -> softmax rows -> ctx = P . pv
// LDS layouts transposed so all microtile reads are contiguous float4.
// Writes ctx directly as fp16 (input to the O-projection MFMA GEMM).
// ---------------------------------------------------------------------------
__global__ __launch_bounds__(256) void attn_kernel(
    const float* __restrict__ Q, const float* __restrict__ PK,
    const float* __restrict__ PV, _Float16* __restrict__ CTXh)
{
    const int bh = blockIdx.x;
    const int b = bh / H_, h = bh % H_;
    __shared__ float pkT[64][68];   // [d][r]
    __shared__ float pv [64][68];   // [r][d]
    __shared__ float Qt [64][68];   // [d][s_local]
    __shared__ float Pt [64][68];   // [r][s_local]
    const int tid = threadIdx.x;
    const int tx = tid & 15, ty = tid >> 4;
    const int w = tid >> 6, lane = tid & 63;

    #pragma unroll
    for (int i = 0; i < 4; ++i) {
        const int flat = i * 1024 + tid * 4;
        const int r = flat >> 6, d = flat & 63;
        const float4 kq = *(const float4*)&PK[(size_t)bh * 4096 + flat];
        const float4 vq = *(const float4*)&PV[(size_t)bh * 4096 + flat];
        pkT[d + 0][r] = kq.x; pkT[d + 1][r] = kq.y;
        pkT[d + 2][r] = kq.z; pkT[d + 3][r] = kq.w;
        *(float4*)&pv[r][d] = vq;
    }

    for (int s0 = 0; s0 < S_; s0 += 64) {
        __syncthreads();   // protects Qt/Pt overwrite vs previous readers
        #pragma unroll
        for (int i = 0; i < 4; ++i) {
            const int flat = i * 1024 + tid * 4;
            const int sl = flat >> 6, d = flat & 63;
            const int s = s0 + sl;
            float4 qv = make_float4(0.f, 0.f, 0.f, 0.f);
            if (s < S_)
                qv = *(const float4*)&Q[((size_t)(b * S_ + s)) * D_ + h * HD_ + d];
            Qt[d + 0][sl] = qv.x; Qt[d + 1][sl] = qv.y;
            Qt[d + 2][sl] = qv.z; Qt[d + 3][sl] = qv.w;
        }
        __syncthreads();

        // scores microtile: s = ty*4+i, r = tx*4+j
        float acc[4][4] = {};
        #pragma unroll 8
        for (int d = 0; d < 64; ++d) {
            const float4 a4 = *(const float4*)&Qt[d][ty * 4];
            const float4 b4 = *(const float4*)&pkT[d][tx * 4];
            const float ax[4] = {a4.x, a4.y, a4.z, a4.w};
            const float bx[4] = {b4.x, b4.y, b4.z, b4.w};
            #pragma unroll
            for (int i = 0; i < 4; ++i)
                #pragma unroll
                for (int j = 0; j < 4; ++j)
                    acc[i][j] += ax[i] * bx[j];
        }
        #pragma unroll
        for (int j = 0; j < 4; ++j)
            #pragma unroll
            for (int i = 0; i < 4; ++i)
                Pt[tx * 4 + j][ty * 4 + i] = acc[i][j] * 0.125f;
        __syncthreads();

        // softmax over r (=lane) for each s column; wave w owns 16 columns
        for (int it = 0; it < 16; ++it) {
            const int s = w * 16 + it;
            const float sc = Pt[lane][s];
            float mx = sc;
            #pragma unroll
            for (int off = 32; off >= 1; off >>= 1)
                mx = fmaxf(mx, __shfl_xor(mx, off, 64));
            const float p = __expf(sc - mx);
            float sum = p;
            #pragma unroll
            for (int off = 32; off >= 1; off >>= 1)
                sum += __shfl_xor(sum, off, 64);
            Pt[lane][s] = p / sum;
        }
        __syncthreads();

        // ctx microtile: s = ty*4+i, d = tx*4+j
        float acc2[4][4] = {};
        #pragma unroll 8
        for (int r = 0; r < 64; ++r) {
            const float4 a4 = *(const float4*)&Pt[r][ty * 4];
            const float4 b4 = *(const float4*)&pv[r][tx * 4];
            const float ax[4] = {a4.x, a4.y, a4.z, a4.w};
            const float bx[4] = {b4.x, b4.y, b4.z, b4.w};
            #pragma unroll
            for (int i = 0; i < 4; ++i)
                #pragma unroll
                for (int j = 0; j < 4; ++j)
                    acc2[i][j] += ax[i] * bx[j];
        }
        #pragma unroll
        for (int i = 0; i < 4; ++i) {
            const int s = s0 + ty * 4 + i;
            if (s < S_) {
                half4_t o = { (_Float16)acc2[i][0], (_Float16)acc2[i][1],
                              (_Float16)acc2[i][2], (_Float16)acc2[i][3] };
                *(half4_t*)&CTXh[((size_t)(b * S_ + s)) * D_ + h * HD_ + tx * 4] = o;
            }
        }
    }
}

// ---------------------------------------------------------------------------
extern "C" void kernel_launch(void* const* d_in, const int* in_sizes, int n_in,
                              void* d_out, int out_size, void* d_ws, size_t ws_size,
                              hipStream_t stream) {
    const float* X   = (const float*)d_in[0];
    const float* Wq  = (const float*)d_in[1];
    const float* bq  = (const float*)d_in[2];
    const float* Wk  = (const float*)d_in[3];
    const float* bk  = (const float*)d_in[4];
    const float* Wv  = (const float*)d_in[5];
    const float* bv  = (const float*)d_in[6];
    const float* Wo  = (const float*)d_in[7];
    const float* bo  = (const float*)d_in[8];
    const float* E_k = (const float*)d_in[9];
    const float* E_v = (const float*)d_in[10];
    float* out = (float*)d_out;

    // workspace layout (bytes)
    char* ws = (char*)d_ws;
    _Float16* Xh  = (_Float16*)ws;                         // MPAD*768*2 = 19.46 MB (reused as ctxh)
    char* p = ws + (size_t)MPAD * D_ * sizeof(_Float16);
    _Float16* Tq = (_Float16*)p; p += (size_t)D_ * D_ * sizeof(_Float16);
    _Float16* Tk = (_Float16*)p; p += (size_t)D_ * D_ * sizeof(_Float16);
    _Float16* Tv = (_Float16*)p; p += (size_t)D_ * D_ * sizeof(_Float16);
    _Float16* To = (_Float16*)p; p += (size_t)D_ * D_ * sizeof(_Float16);
    float* Cbuf = (float*)p;    p += (size_t)MPAD * D_ * sizeof(float);   // 38.93 MB
    float* pk   = (float*)p;    p += (size_t)(B_ * H_) * 4096 * sizeof(float);
    float* pv   = (float*)p;

    const dim3 gw(24, 24, 4);
    const dim3 gg(D_ / 128, MPAD / 128);   // (6, 99)

    transpose_w_kernel<<<gw, 256, 0, stream>>>(Wq, Wk, Wv, Wo, Tq, Tk, Tv, To);
    conv_x_kernel<<<(MPAD * D_ / 4 + 255) / 256, 256, 0, stream>>>(
        X, Xh, M_ * D_, MPAD * D_);

    gemm_f16_kernel<<<gg, 256, 0, stream>>>(Xh, Tk, bk, Cbuf, MPAD);       // k
    project_kernel <<<B_ * H_, 256, 0, stream>>>(Cbuf, E_k, pk);           // pk
    gemm_f16_kernel<<<gg, 256, 0, stream>>>(Xh, Tv, bv, Cbuf, MPAD);       // v
    project_kernel <<<B_ * H_, 256, 0, stream>>>(Cbuf, E_v, pv);           // pv
    gemm_f16_kernel<<<gg, 256, 0, stream>>>(Xh, Tq, bq, Cbuf, MPAD);       // q
    attn_kernel    <<<B_ * H_, 256, 0, stream>>>(Cbuf, pk, pv, Xh);        // ctx (fp16, reuses Xh)
    gemm_f16_kernel<<<gg, 256, 0, stream>>>(Xh, To, bo, out, M_);          // out
}

// Round 3
// 283.256 us; speedup vs baseline: 4.3885x; 1.7337x over previous
//
#include <hip/hip_runtime.h>
#include <math.h>

#define B_   64
#define S_   197
#define D_   768
#define H_   12
#define HD_  64
#define M_   (B_ * S_)     // 12608
#define MPAD 12672         // 99*128
#define KE   224           // padded contraction length for E-projection (7*32)
#define BH_  (B_ * H_)     // 768

typedef _Float16 half8_t __attribute__((ext_vector_type(8)));
typedef _Float16 half4_t __attribute__((ext_vector_type(4)));
typedef _Float16 half2_t __attribute__((ext_vector_type(2)));
typedef float floatx4 __attribute__((ext_vector_type(4)));

// async global->LDS DMA, 16B per lane; lptr must be wave-uniform (HW adds lane*16)
#define LDS_DMA16(gptr, lptr) \
  __builtin_amdgcn_global_load_lds((const __attribute__((address_space(1))) void*)(gptr), \
                                   (__attribute__((address_space(3))) void*)(lptr), 16, 0, 0)

// ---------------------------------------------------------------------------
// Fused prep: [0,9504) convert X->fp16 (zero-pad rows to MPAD);
// [9504,11808) transpose+convert 4 weight matrices; [11808,11810) E_k/E_v ->
// fp16 transposed [64][KE], zero-padded s>=197.
// ---------------------------------------------------------------------------
__global__ __launch_bounds__(256) void prep_kernel(
    const float* __restrict__ X,
    const float* __restrict__ Wq, const float* __restrict__ Wk,
    const float* __restrict__ Wv, const float* __restrict__ Wo,
    const float* __restrict__ Ek, const float* __restrict__ Ev,
    _Float16* __restrict__ Xh,
    _Float16* __restrict__ Tq, _Float16* __restrict__ Tk,
    _Float16* __restrict__ Tv, _Float16* __restrict__ To,
    _Float16* __restrict__ EkT, _Float16* __restrict__ EvT)
{
    __shared__ float tile[32][33];
    const int bid = blockIdx.x, tid = threadIdx.x;
    if (bid < 9504) {
        const int i4 = (bid * 256 + tid) * 4;
        float4 v = make_float4(0.f, 0.f, 0.f, 0.f);
        if (i4 < M_ * D_) v = *(const float4*)&X[i4];
        half4_t o = { (_Float16)v.x, (_Float16)v.y, (_Float16)v.z, (_Float16)v.w };
        *(half4_t*)&Xh[i4] = o;
        return;
    }
    int b2 = bid - 9504;
    if (b2 < 2304) {
        const int z = b2 / 576, rem = b2 % 576;
        const int bx = rem % 24, by = rem / 24;
        const float* W = (z == 0) ? Wq : (z == 1) ? Wk : (z == 2) ? Wv : Wo;
        _Float16* T = (z == 0) ? Tq : (z == 1) ? Tk : (z == 2) ? Tv : To;
        const int n0 = bx * 32, k0 = by * 32;
        const int r = tid >> 3, c4 = (tid & 7) * 4;
        *(float4*)&tile[r][c4] = *(const float4*)&W[(size_t)(k0 + r) * D_ + n0 + c4];
        __syncthreads();
        half4_t o = { (_Float16)tile[c4 + 0][r], (_Float16)tile[c4 + 1][r],
                      (_Float16)tile[c4 + 2][r], (_Float16)tile[c4 + 3][r] };
        *(half4_t*)&T[(size_t)(n0 + r) * D_ + k0 + c4] = o;
        return;
    }
    b2 -= 2304;   // 0 or 1
    const float* E = b2 ? Ev : Ek;
    _Float16* ET = b2 ? EvT : EkT;
    for (int i = tid; i < 64 * KE; i += 256) {
        const int rr = i / KE, s = i % KE;
        ET[i] = (_Float16)((s < S_) ? E[s * 64 + rr] : 0.f);
    }
}

// ---------------------------------------------------------------------------
// C = A @ Bt^T + bias.  A [MPAD][768] fp16, Bt [768][768] fp16 (n-major).
// 128x128 tile, BK=32, 4 waves, global_load_lds staging (m97 structure).
// blockIdx.z selects weight/bias/output; fp16 out (qkv) or fp32 out (final).
// ---------------------------------------------------------------------------
__global__ __launch_bounds__(256) void gemm_kernel(
    const _Float16* __restrict__ A,
    const _Float16* __restrict__ B0, const _Float16* __restrict__ B1,
    const _Float16* __restrict__ B2,
    const float* __restrict__ bias0, const float* __restrict__ bias1,
    const float* __restrict__ bias2,
    _Float16* __restrict__ O0, _Float16* __restrict__ O1,
    _Float16* __restrict__ O2,
    float* __restrict__ O32, int guardM)
{
    __shared__ _Float16 Ah[128 * 32];
    __shared__ _Float16 Bh[128 * 32];
    const int z = blockIdx.z;
    const _Float16* Bt = (z == 0) ? B0 : (z == 1) ? B1 : B2;
    const float* bias  = (z == 0) ? bias0 : (z == 1) ? bias1 : bias2;
    _Float16* O16      = (z == 0) ? O0 : (z == 1) ? O1 : O2;

    const int tid = threadIdx.x;
    const int m0 = blockIdx.y * 128, n0 = blockIdx.x * 128;
    const int w = tid >> 6, lane = tid & 63;
    const int fr = lane & 15, kofs = (lane >> 4) * 8;
    const int jrow = lane >> 2;          // 0..15
    const int jcol = (lane & 3) * 8;     // half offset within 32
    const int wm = (w >> 1) * 64, wn = (w & 1) * 64;

    floatx4 acc[4][4] = {};

    for (int k0 = 0; k0 < D_; k0 += 32) {
        #pragma unroll
        for (int j = 0; j < 2; ++j) {
            const int r = w * 32 + j * 16 + jrow;
            LDS_DMA16(&A[(size_t)(m0 + r) * D_ + k0 + jcol],
                      &Ah[w * 1024 + j * 512]);
            LDS_DMA16(&Bt[(size_t)(n0 + r) * D_ + k0 + jcol],
                      &Bh[w * 1024 + j * 512]);
        }
        __syncthreads();
        half8_t af[4], bf[4];
        #pragma unroll
        for (int i = 0; i < 4; ++i) {
            af[i] = *(const half8_t*)&Ah[(wm + i * 16 + fr) * 32 + kofs];
            bf[i] = *(const half8_t*)&Bh[(wn + i * 16 + fr) * 32 + kofs];
        }
        #pragma unroll
        for (int mi = 0; mi < 4; ++mi)
            #pragma unroll
            for (int ni = 0; ni < 4; ++ni)
                acc[mi][ni] = __builtin_amdgcn_mfma_f32_16x16x32_f16(
                    af[mi], bf[ni], acc[mi][ni], 0, 0, 0);
        __syncthreads();
    }

    const int col = lane & 15, rq = (lane >> 4) * 4;
    #pragma unroll
    for (int ni = 0; ni < 4; ++ni) {
        const int n = n0 + wn + ni * 16 + col;
        const float bv = bias[n];
        #pragma unroll
        for (int mi = 0; mi < 4; ++mi) {
            #pragma unroll
            for (int i = 0; i < 4; ++i) {
                const int m = m0 + wm + mi * 16 + rq + i;
                if (O32) {
                    if (m < guardM) O32[(size_t)m * D_ + n] = acc[mi][ni][i] + bv;
                } else {
                    O16[(size_t)m * D_ + n] = (_Float16)(acc[mi][ni][i] + bv);
                }
            }
        }
    }
}

// ---------------------------------------------------------------------------
// Low-rank projection via MFMA: which=0: pk[r][d] = sum_s EkT[r][s] K[s][d];
// which=1: pvT[d][r] (transposed store).  One block per (which,b,h).
// K/V slice staged into LDS [s][66] (2-way-free banking), B-frags assembled
// from scalar u16 reads, A-frags straight from global EhT.
// ---------------------------------------------------------------------------
__global__ __launch_bounds__(256) void proj_kernel(
    const _Float16* __restrict__ Kh, const _Float16* __restrict__ Vh,
    const _Float16* __restrict__ EkT, const _Float16* __restrict__ EvT,
    _Float16* __restrict__ pk, _Float16* __restrict__ pvT)
{
    __shared__ _Float16 ks[KE * 66];
    const int gb = blockIdx.x;
    const int which = gb / BH_;
    const int bh = gb - which * BH_;
    const int b = bh / H_, h = bh % H_;
    const _Float16* KV = which ? Vh : Kh;
    const _Float16* ET = which ? EvT : EkT;
    const int tid = threadIdx.x, w = tid >> 6, lane = tid & 63;
    const int l15 = lane & 15, quad = lane >> 4;

    // stage [224][64] slice (rows b*197+s always in-bounds; s>=197 rows are
    // multiplied by E's zero padding)
    #pragma unroll
    for (int i = 0; i < 7; ++i) {
        const int s = i * 32 + (tid >> 3);
        const int d0 = (tid & 7) * 8;
        const half8_t v = *(const half8_t*)&KV[(size_t)(b * S_ + s) * D_ + h * HD_ + d0];
        #pragma unroll
        for (int j = 0; j < 4; ++j) {
            half2_t t2 = { v[2 * j], v[2 * j + 1] };
            *(half2_t*)&ks[s * 66 + d0 + 2 * j] = t2;
        }
    }
    __syncthreads();

    floatx4 acc[4] = {};
    const int rrow = w * 16 + l15;       // A m-index = r
    #pragma unroll
    for (int k7 = 0; k7 < 7; ++k7) {
        const int s0 = k7 * 32;
        const half8_t ae = *(const half8_t*)&ET[rrow * KE + s0 + quad * 8];
        #pragma unroll
        for (int ni = 0; ni < 4; ++ni) {
            const int dcol = ni * 16 + l15;
            const int sb = s0 + quad * 8;
            half8_t bf;
            #pragma unroll
            for (int j = 0; j < 8; ++j) bf[j] = ks[(sb + j) * 66 + dcol];
            acc[ni] = __builtin_amdgcn_mfma_f32_16x16x32_f16(ae, bf, acc[ni], 0, 0, 0);
        }
    }

    const size_t obase = (size_t)bh * 4096;
    if (which == 0) {
        #pragma unroll
        for (int ni = 0; ni < 4; ++ni)
            #pragma unroll
            for (int i = 0; i < 4; ++i)
                pk[obase + (w * 16 + quad * 4 + i) * 64 + ni * 16 + l15] =
                    (_Float16)acc[ni][i];
    } else {
        #pragma unroll
        for (int ni = 0; ni < 4; ++ni) {
            half4_t o = { (_Float16)acc[ni][0], (_Float16)acc[ni][1],
                          (_Float16)acc[ni][2], (_Float16)acc[ni][3] };
            *(half4_t*)&pvT[obase + (ni * 16 + l15) * 64 + w * 16 + quad * 4] = o;
        }
    }
}

// ---------------------------------------------------------------------------
// MFMA attention: one block per (b,h), barrier-free. pk/pvT fragments hoisted
// into registers; Q A-frags direct from global; only P round-trips LDS
// (wave-private 16-row band). 13 row-tiles of 16 split across 4 waves.
// ---------------------------------------------------------------------------
__global__ __launch_bounds__(256) void attn_kernel(
    const _Float16* __restrict__ Qh, const _Float16* __restrict__ pk,
    const _Float16* __restrict__ pvT, _Float16* __restrict__ CTXh)
{
    __shared__ _Float16 P[64 * 80];
    const int bh = blockIdx.x, b = bh / H_, h = bh % H_;
    const int tid = threadIdx.x, w = tid >> 6, lane = tid & 63;
    const int l15 = lane & 15, quad = lane >> 4;
    const _Float16* pkB = pk + (size_t)bh * 4096;
    const _Float16* pvB = pvT + (size_t)bh * 4096;
    const size_t qbase = (size_t)(b * S_) * D_ + h * HD_;

    half8_t bk[4][2], bv[4][2];
    #pragma unroll
    for (int ni = 0; ni < 4; ++ni)
        #pragma unroll
        for (int kk = 0; kk < 2; ++kk) {
            bk[ni][kk] = *(const half8_t*)&pkB[(ni * 16 + l15) * 64 + kk * 32 + quad * 8];
            bv[ni][kk] = *(const half8_t*)&pvB[(ni * 16 + l15) * 64 + kk * 32 + quad * 8];
        }

    for (int t = w; t < 13; t += 4) {
        const int srow = t * 16;
        floatx4 acc[4] = {};
        #pragma unroll
        for (int kk = 0; kk < 2; ++kk) {
            const half8_t aq = *(const half8_t*)
                &Qh[qbase + (size_t)(srow + l15) * D_ + kk * 32 + quad * 8];
            #pragma unroll
            for (int ni = 0; ni < 4; ++ni)
                acc[ni] = __builtin_amdgcn_mfma_f32_16x16x32_f16(
                    aq, bk[ni][kk], acc[ni], 0, 0, 0);
        }
        // in-register softmax over r for each of this lane's 4 rows
        float p[4][4];
        #pragma unroll
        for (int i = 0; i < 4; ++i) {
            const float s0 = acc[0][i] * 0.125f, s1 = acc[1][i] * 0.125f;
            const float s2 = acc[2][i] * 0.125f, s3 = acc[3][i] * 0.125f;
            float mx = fmaxf(fmaxf(s0, s1), fmaxf(s2, s3));
            #pragma unroll
            for (int off = 1; off < 16; off <<= 1)
                mx = fmaxf(mx, __shfl_xor(mx, off, 64));
            const float e0 = __expf(s0 - mx), e1 = __expf(s1 - mx);
            const float e2 = __expf(s2 - mx), e3 = __expf(s3 - mx);
            float sm = e0 + e1 + e2 + e3;
            #pragma unroll
            for (int off = 1; off < 16; off <<= 1)
                sm += __shfl_xor(sm, off, 64);
            const float inv = 1.f / sm;
            p[0][i] = e0 * inv; p[1][i] = e1 * inv;
            p[2][i] = e2 * inv; p[3][i] = e3 * inv;
        }
        // C-layout -> A-layout via wave-private LDS band
        #pragma unroll
        for (int ni = 0; ni < 4; ++ni)
            #pragma unroll
            for (int i = 0; i < 4; ++i)
                P[(w * 16 + quad * 4 + i) * 80 + ni * 16 + l15] = (_Float16)p[ni][i];

        floatx4 accv[4] = {};
        #pragma unroll
        for (int kk = 0; kk < 2; ++kk) {
            const half8_t ap = *(const half8_t*)&P[(w * 16 + l15) * 80 + kk * 32 + quad * 8];
            #pragma unroll
            for (int ni = 0; ni < 4; ++ni)
                accv[ni] = __builtin_amdgcn_mfma_f32_16x16x32_f16(
                    ap, bv[ni][kk], accv[ni], 0, 0, 0);
        }
        #pragma unroll
        for (int ni = 0; ni < 4; ++ni)
            #pragma unroll
            for (int i = 0; i < 4; ++i) {
                const int s = srow + quad * 4 + i;
                if (s < S_)
                    CTXh[qbase + (size_t)s * D_ + ni * 16 + l15] = (_Float16)accv[ni][i];
            }
    }
}

// ---------------------------------------------------------------------------
extern "C" void kernel_launch(void* const* d_in, const int* in_sizes, int n_in,
                              void* d_out, int out_size, void* d_ws, size_t ws_size,
                              hipStream_t stream) {
    const float* X   = (const float*)d_in[0];
    const float* Wq  = (const float*)d_in[1];
    const float* bq  = (const float*)d_in[2];
    const float* Wk  = (const float*)d_in[3];
    const float* bk  = (const float*)d_in[4];
    const float* Wv  = (const float*)d_in[5];
    const float* bv  = (const float*)d_in[6];
    const float* Wo  = (const float*)d_in[7];
    const float* bo  = (const float*)d_in[8];
    const float* E_k = (const float*)d_in[9];
    const float* E_v = (const float*)d_in[10];
    float* out = (float*)d_out;

    char* p = (char*)d_ws;
    _Float16* Xh  = (_Float16*)p; p += (size_t)MPAD * D_ * 2;   // reused as CTXh
    _Float16* Tq  = (_Float16*)p; p += (size_t)D_ * D_ * 2;
    _Float16* Tk  = (_Float16*)p; p += (size_t)D_ * D_ * 2;
    _Float16* Tv  = (_Float16*)p; p += (size_t)D_ * D_ * 2;
    _Float16* To  = (_Float16*)p; p += (size_t)D_ * D_ * 2;
    _Float16* Qh  = (_Float16*)p; p += (size_t)MPAD * D_ * 2;
    _Float16* Kh  = (_Float16*)p; p += (size_t)MPAD * D_ * 2;
    _Float16* Vh  = (_Float16*)p; p += (size_t)MPAD * D_ * 2;
    _Float16* EkT = (_Float16*)p; p += (size_t)64 * KE * 2;
    _Float16* EvT = (_Float16*)p; p += (size_t)64 * KE * 2;
    _Float16* pkb = (_Float16*)p; p += (size_t)BH_ * 4096 * 2;
    _Float16* pvb = (_Float16*)p;

    prep_kernel<<<11810, 256, 0, stream>>>(X, Wq, Wk, Wv, Wo, E_k, E_v,
                                           Xh, Tq, Tk, Tv, To, EkT, EvT);
    gemm_kernel<<<dim3(6, 99, 3), 256, 0, stream>>>(
        Xh, Tk, Tv, Tq, bk, bv, bq, Kh, Vh, Qh, nullptr, MPAD);
    proj_kernel<<<2 * BH_, 256, 0, stream>>>(Kh, Vh, EkT, EvT, pkb, pvb);
    attn_kernel<<<BH_, 256, 0, stream>>>(Qh, pkb, pvb, Xh);
    gemm_kernel<<<dim3(6, 99, 1), 256, 0, stream>>>(
        Xh, To, To, To, bo, bo, bo, nullptr, nullptr, nullptr, out, M_);
}

// Round 4
// 243.608 us; speedup vs baseline: 5.1028x; 1.1628x over previous
//
#include <hip/hip_runtime.h>
#include <math.h>

#define B_   64
#define S_   197
#define D_   768
#define H_   12
#define HD_  64
#define M_   (B_ * S_)     // 12608
#define MPAD 12672         // 99*128
#define KE   224           // padded contraction length for E-projection (7*32)
#define BH_  (B_ * H_)     // 768

typedef _Float16 half8_t __attribute__((ext_vector_type(8)));
typedef _Float16 half4_t __attribute__((ext_vector_type(4)));
typedef _Float16 half2_t __attribute__((ext_vector_type(2)));
typedef float floatx4 __attribute__((ext_vector_type(4)));

// async global->LDS DMA, 16B per lane; lptr must be wave-uniform (HW adds lane*16)
#define LDS_DMA16(gptr, lptr) \
  __builtin_amdgcn_global_load_lds((const __attribute__((address_space(1))) void*)(gptr), \
                                   (__attribute__((address_space(3))) void*)(lptr), 16, 0, 0)

// ---------------------------------------------------------------------------
// Fused prep: [0,9504) convert X->fp16 (zero-pad rows to MPAD);
// [9504,11808) transpose+convert weights: Wk/Wv/Wq -> Tcat rows [0,2304),
// Wo -> To; [11808,11810) E_k/E_v -> fp16 transposed [64][KE], zero-padded.
// ---------------------------------------------------------------------------
__global__ __launch_bounds__(256) void prep_kernel(
    const float* __restrict__ X,
    const float* __restrict__ Wq, const float* __restrict__ Wk,
    const float* __restrict__ Wv, const float* __restrict__ Wo,
    const float* __restrict__ Ek, const float* __restrict__ Ev,
    _Float16* __restrict__ Xh,
    _Float16* __restrict__ Tcat, _Float16* __restrict__ To,
    _Float16* __restrict__ EkT, _Float16* __restrict__ EvT)
{
    __shared__ float tile[32][33];
    const int bid = blockIdx.x, tid = threadIdx.x;
    if (bid < 9504) {
        const int i4 = (bid * 256 + tid) * 4;
        float4 v = make_float4(0.f, 0.f, 0.f, 0.f);
        if (i4 < M_ * D_) v = *(const float4*)&X[i4];
        half4_t o = { (_Float16)v.x, (_Float16)v.y, (_Float16)v.z, (_Float16)v.w };
        *(half4_t*)&Xh[i4] = o;
        return;
    }
    int b2 = bid - 9504;
    if (b2 < 2304) {
        const int z = b2 / 576, rem = b2 % 576;
        const int bx = rem % 24, by = rem / 24;
        // z: 0->Wk, 1->Wv, 2->Wq (into Tcat), 3->Wo (into To)
        const float* W = (z == 0) ? Wk : (z == 1) ? Wv : (z == 2) ? Wq : Wo;
        _Float16* T = (z < 3) ? (Tcat + (size_t)z * D_ * D_) : To;
        const int n0 = bx * 32, k0 = by * 32;
        const int r = tid >> 3, c4 = (tid & 7) * 4;
        *(float4*)&tile[r][c4] = *(const float4*)&W[(size_t)(k0 + r) * D_ + n0 + c4];
        __syncthreads();
        half4_t o = { (_Float16)tile[c4 + 0][r], (_Float16)tile[c4 + 1][r],
                      (_Float16)tile[c4 + 2][r], (_Float16)tile[c4 + 3][r] };
        *(half4_t*)&T[(size_t)(n0 + r) * D_ + k0 + c4] = o;
        return;
    }
    b2 -= 2304;   // 0 or 1
    const float* E = b2 ? Ev : Ek;
    _Float16* ET = b2 ? EvT : EkT;
    for (int i = tid; i < 64 * KE; i += 256) {
        const int rr = i / KE, s = i % KE;
        ET[i] = (_Float16)((s < S_) ? E[s * 64 + rr] : 0.f);
    }
}

// ---------------------------------------------------------------------------
// C = A @ W^T + bias.  A [MPAD][768] fp16, W [jCount*128][768] fp16 (n-major).
// 128x128 tile, BK=32, 4 waves, global_load_lds staging with XOR chunk
// swizzle (bank-conflict-free frag reads), XCD-aware block mapping, and a
// wave-private LDS-transpose epilogue for coalesced fp16 stores.
// z = j/6 selects bias/output (QKV); O32 path = direct fp32 stores.
// ---------------------------------------------------------------------------
union GemmSmem {
    _Float16 stage[2][128 * 32];   // [0]=A, [1]=B
    _Float16 ct[4][64 * 68];       // epilogue transpose, per-wave
};

__global__ __launch_bounds__(256) void gemm_kernel(
    const _Float16* __restrict__ A, const _Float16* __restrict__ W,
    const float* __restrict__ b0, const float* __restrict__ b1,
    const float* __restrict__ b2,
    _Float16* __restrict__ O0, _Float16* __restrict__ O1,
    _Float16* __restrict__ O2,
    float* __restrict__ O32, int jCount, int guardM)
{
    __shared__ GemmSmem sm;
    // XCD-aware decode: consecutive m-blocks for a given XCD (bid%8)
    const int xcd = blockIdx.x & 7;
    const int t = blockIdx.x >> 3;
    const int slot = t / jCount, j = t - slot * jCount;
    const int m_blk = slot * 8 + xcd;
    if (m_blk >= MPAD / 128) return;
    const int m0 = m_blk * 128;

    const int z = j / 6;
    const int n_in = (j - z * 6) * 128;
    const float* bias = (z == 0) ? b0 : (z == 1) ? b1 : b2;
    _Float16* O16     = (z == 0) ? O0 : (z == 1) ? O1 : O2;

    const int tid = threadIdx.x;
    const int w = tid >> 6, lane = tid & 63;
    const int fr = lane & 15, quad = lane >> 4;
    const int jrow = lane >> 2;
    const int csw = ((lane & 3) ^ ((lane >> 3) & 3)) * 8;   // swizzled src chunk
    const int ksw = (quad ^ ((fr >> 1) & 3)) * 8;           // swizzled read slot
    const int wm = (w >> 1) * 64, wn = (w & 1) * 64;

    floatx4 acc[4][4] = {};

    for (int k0 = 0; k0 < D_; k0 += 32) {
        #pragma unroll
        for (int jj = 0; jj < 2; ++jj) {
            const int r = w * 32 + jj * 16 + jrow;
            LDS_DMA16(&A[(size_t)(m0 + r) * D_ + k0 + csw],
                      &sm.stage[0][w * 1024 + jj * 512]);
            LDS_DMA16(&W[(size_t)(j * 128 + r) * D_ + k0 + csw],
                      &sm.stage[1][w * 1024 + jj * 512]);
        }
        __syncthreads();
        half8_t af[4], bf[4];
        #pragma unroll
        for (int i = 0; i < 4; ++i) {
            af[i] = *(const half8_t*)&sm.stage[0][(wm + i * 16 + fr) * 32 + ksw];
            bf[i] = *(const half8_t*)&sm.stage[1][(wn + i * 16 + fr) * 32 + ksw];
        }
        #pragma unroll
        for (int mi = 0; mi < 4; ++mi)
            #pragma unroll
            for (int ni = 0; ni < 4; ++ni)
                acc[mi][ni] = __builtin_amdgcn_mfma_f32_16x16x32_f16(
                    af[mi], bf[ni], acc[mi][ni], 0, 0, 0);
        __syncthreads();
    }

    // bias per ni-column for this lane
    float bval[4];
    #pragma unroll
    for (int ni = 0; ni < 4; ++ni)
        bval[ni] = bias[n_in + wn + ni * 16 + fr];

    if (O32) {
        const int rq = quad * 4;
        #pragma unroll
        for (int ni = 0; ni < 4; ++ni) {
            const int n = n_in + wn + ni * 16 + fr;
            #pragma unroll
            for (int mi = 0; mi < 4; ++mi)
                #pragma unroll
                for (int i = 0; i < 4; ++i) {
                    const int m = m0 + wm + mi * 16 + rq + i;
                    if (m < guardM)
                        O32[(size_t)m * D_ + n] = acc[mi][ni][i] + bval[ni];
                }
        }
    } else {
        // stage into wave-private LDS tile (64x68, 2-way banking = free)
        #pragma unroll
        for (int mi = 0; mi < 4; ++mi)
            #pragma unroll
            for (int ni = 0; ni < 4; ++ni)
                #pragma unroll
                for (int i = 0; i < 4; ++i)
                    sm.ct[w][(mi * 16 + quad * 4 + i) * 68 + ni * 16 + fr] =
                        (_Float16)(acc[mi][ni][i] + bval[ni]);
        // coalesced half8 row stores: 8 lanes cover one 128B row
        #pragma unroll
        for (int pass = 0; pass < 8; ++pass) {
            const int rr = pass * 8 + (lane >> 3);
            const int cc = (lane & 7) * 8;
            const half8_t v = *(const half8_t*)&sm.ct[w][rr * 68 + cc];
            *(half8_t*)&O16[(size_t)(m0 + wm + rr) * D_ + n_in + wn + cc] = v;
        }
    }
}

// ---------------------------------------------------------------------------
// Low-rank projection via MFMA: which=0: pk[r][d] = sum_s EkT[r][s] K[s][d];
// which=1: pvT[d][r] (transposed store).  One block per (which,b,h).
// ---------------------------------------------------------------------------
__global__ __launch_bounds__(256) void proj_kernel(
    const _Float16* __restrict__ Kh, const _Float16* __restrict__ Vh,
    const _Float16* __restrict__ EkT, const _Float16* __restrict__ EvT,
    _Float16* __restrict__ pk, _Float16* __restrict__ pvT)
{
    __shared__ _Float16 ks[KE * 66];
    const int gb = blockIdx.x;
    const int which = gb / BH_;
    const int bh = gb - which * BH_;
    const int b = bh / H_, h = bh % H_;
    const _Float16* KV = which ? Vh : Kh;
    const _Float16* ET = which ? EvT : EkT;
    const int tid = threadIdx.x, w = tid >> 6, lane = tid & 63;
    const int l15 = lane & 15, quad = lane >> 4;

    #pragma unroll
    for (int i = 0; i < 7; ++i) {
        const int s = i * 32 + (tid >> 3);
        const int d0 = (tid & 7) * 8;
        const half8_t v = *(const half8_t*)&KV[(size_t)(b * S_ + s) * D_ + h * HD_ + d0];
        #pragma unroll
        for (int jj = 0; jj < 4; ++jj) {
            half2_t t2 = { v[2 * jj], v[2 * jj + 1] };
            *(half2_t*)&ks[s * 66 + d0 + 2 * jj] = t2;
        }
    }
    __syncthreads();

    floatx4 acc[4] = {};
    const int rrow = w * 16 + l15;
    #pragma unroll
    for (int k7 = 0; k7 < 7; ++k7) {
        const int s0 = k7 * 32;
        const half8_t ae = *(const half8_t*)&ET[rrow * KE + s0 + quad * 8];
        #pragma unroll
        for (int ni = 0; ni < 4; ++ni) {
            const int dcol = ni * 16 + l15;
            const int sb = s0 + quad * 8;
            half8_t bf;
            #pragma unroll
            for (int jj = 0; jj < 8; ++jj) bf[jj] = ks[(sb + jj) * 66 + dcol];
            acc[ni] = __builtin_amdgcn_mfma_f32_16x16x32_f16(ae, bf, acc[ni], 0, 0, 0);
        }
    }

    const size_t obase = (size_t)bh * 4096;
    if (which == 0) {
        #pragma unroll
        for (int ni = 0; ni < 4; ++ni)
            #pragma unroll
            for (int i = 0; i < 4; ++i)
                pk[obase + (w * 16 + quad * 4 + i) * 64 + ni * 16 + l15] =
                    (_Float16)acc[ni][i];
    } else {
        #pragma unroll
        for (int ni = 0; ni < 4; ++ni) {
            half4_t o = { (_Float16)acc[ni][0], (_Float16)acc[ni][1],
                          (_Float16)acc[ni][2], (_Float16)acc[ni][3] };
            *(half4_t*)&pvT[obase + (ni * 16 + l15) * 64 + w * 16 + quad * 4] = o;
        }
    }
}

// ---------------------------------------------------------------------------
// MFMA attention: one block per (b,h), barrier-free. pk/pvT frags in regs;
// Q A-frags direct from global; P round-trips a wave-private LDS band.
// ---------------------------------------------------------------------------
__global__ __launch_bounds__(256) void attn_kernel(
    const _Float16* __restrict__ Qh, const _Float16* __restrict__ pk,
    const _Float16* __restrict__ pvT, _Float16* __restrict__ CTXh)
{
    __shared__ _Float16 P[64 * 80];
    const int bh = blockIdx.x, b = bh / H_, h = bh % H_;
    const int tid = threadIdx.x, w = tid >> 6, lane = tid & 63;
    const int l15 = lane & 15, quad = lane >> 4;
    const _Float16* pkB = pk + (size_t)bh * 4096;
    const _Float16* pvB = pvT + (size_t)bh * 4096;
    const size_t qbase = (size_t)(b * S_) * D_ + h * HD_;

    half8_t bk[4][2], bv[4][2];
    #pragma unroll
    for (int ni = 0; ni < 4; ++ni)
        #pragma unroll
        for (int kk = 0; kk < 2; ++kk) {
            bk[ni][kk] = *(const half8_t*)&pkB[(ni * 16 + l15) * 64 + kk * 32 + quad * 8];
            bv[ni][kk] = *(const half8_t*)&pvB[(ni * 16 + l15) * 64 + kk * 32 + quad * 8];
        }

    for (int t = w; t < 13; t += 4) {
        const int srow = t * 16;
        floatx4 acc[4] = {};
        #pragma unroll
        for (int kk = 0; kk < 2; ++kk) {
            const half8_t aq = *(const half8_t*)
                &Qh[qbase + (size_t)(srow + l15) * D_ + kk * 32 + quad * 8];
            #pragma unroll
            for (int ni = 0; ni < 4; ++ni)
                acc[ni] = __builtin_amdgcn_mfma_f32_16x16x32_f16(
                    aq, bk[ni][kk], acc[ni], 0, 0, 0);
        }
        float p[4][4];
        #pragma unroll
        for (int i = 0; i < 4; ++i) {
            const float s0 = acc[0][i] * 0.125f, s1 = acc[1][i] * 0.125f;
            const float s2 = acc[2][i] * 0.125f, s3 = acc[3][i] * 0.125f;
            float mx = fmaxf(fmaxf(s0, s1), fmaxf(s2, s3));
            #pragma unroll
            for (int off = 1; off < 16; off <<= 1)
                mx = fmaxf(mx, __shfl_xor(mx, off, 64));
            const float e0 = __expf(s0 - mx), e1 = __expf(s1 - mx);
            const float e2 = __expf(s2 - mx), e3 = __expf(s3 - mx);
            float sme = e0 + e1 + e2 + e3;
            #pragma unroll
            for (int off = 1; off < 16; off <<= 1)
                sme += __shfl_xor(sme, off, 64);
            const float inv = 1.f / sme;
            p[0][i] = e0 * inv; p[1][i] = e1 * inv;
            p[2][i] = e2 * inv; p[3][i] = e3 * inv;
        }
        #pragma unroll
        for (int ni = 0; ni < 4; ++ni)
            #pragma unroll
            for (int i = 0; i < 4; ++i)
                P[(w * 16 + quad * 4 + i) * 80 + ni * 16 + l15] = (_Float16)p[ni][i];

        floatx4 accv[4] = {};
        #pragma unroll
        for (int kk = 0; kk < 2; ++kk) {
            const half8_t ap = *(const half8_t*)&P[(w * 16 + l15) * 80 + kk * 32 + quad * 8];
            #pragma unroll
            for (int ni = 0; ni < 4; ++ni)
                accv[ni] = __builtin_amdgcn_mfma_f32_16x16x32_f16(
                    ap, bv[ni][kk], accv[ni], 0, 0, 0);
        }
        #pragma unroll
        for (int ni = 0; ni < 4; ++ni)
            #pragma unroll
            for (int i = 0; i < 4; ++i) {
                const int s = srow + quad * 4 + i;
                if (s < S_)
                    CTXh[qbase + (size_t)s * D_ + ni * 16 + l15] = (_Float16)accv[ni][i];
            }
    }
}

// ---------------------------------------------------------------------------
extern "C" void kernel_launch(void* const* d_in, const int* in_sizes, int n_in,
                              void* d_out, int out_size, void* d_ws, size_t ws_size,
                              hipStream_t stream) {
    const float* X   = (const float*)d_in[0];
    const float* Wq  = (const float*)d_in[1];
    const float* bq  = (const float*)d_in[2];
    const float* Wk  = (const float*)d_in[3];
    const float* bk  = (const float*)d_in[4];
    const float* Wv  = (const float*)d_in[5];
    const float* bv  = (const float*)d_in[6];
    const float* Wo  = (const float*)d_in[7];
    const float* bo  = (const float*)d_in[8];
    const float* E_k = (const float*)d_in[9];
    const float* E_v = (const float*)d_in[10];
    float* out = (float*)d_out;

    char* p = (char*)d_ws;
    _Float16* Xh   = (_Float16*)p; p += (size_t)MPAD * D_ * 2;   // reused as CTXh
    _Float16* Tcat = (_Float16*)p; p += (size_t)3 * D_ * D_ * 2;
    _Float16* To   = (_Float16*)p; p += (size_t)D_ * D_ * 2;
    _Float16* Qh   = (_Float16*)p; p += (size_t)MPAD * D_ * 2;
    _Float16* Kh   = (_Float16*)p; p += (size_t)MPAD * D_ * 2;
    _Float16* Vh   = (_Float16*)p; p += (size_t)MPAD * D_ * 2;
    _Float16* EkT  = (_Float16*)p; p += (size_t)64 * KE * 2;
    _Float16* EvT  = (_Float16*)p; p += (size_t)64 * KE * 2;
    _Float16* pkb  = (_Float16*)p; p += (size_t)BH_ * 4096 * 2;
    _Float16* pvb  = (_Float16*)p;

    prep_kernel<<<11810, 256, 0, stream>>>(X, Wq, Wk, Wv, Wo, E_k, E_v,
                                           Xh, Tcat, To, EkT, EvT);
    // QKV: 8 XCDs x 13 m-slots x 18 (n,z) blocks
    gemm_kernel<<<8 * 13 * 18, 256, 0, stream>>>(
        Xh, Tcat, bk, bv, bq, Kh, Vh, Qh, nullptr, 18, MPAD);
    proj_kernel<<<2 * BH_, 256, 0, stream>>>(Kh, Vh, EkT, EvT, pkb, pvb);
    attn_kernel<<<BH_, 256, 0, stream>>>(Qh, pkb, pvb, Xh);
    // O-projection: 8 x 13 x 6
    gemm_kernel<<<8 * 13 * 6, 256, 0, stream>>>(
        Xh, To, bo, bo, bo, nullptr, nullptr, nullptr, out, 6, M_);
}